// Round 11
// baseline (263.411 us; speedup 1.0000x reference)
//
#include <hip/hip_runtime.h>

#define HH_EPS 1e-8f

constexpr int D     = 2048;            // feature dim
constexpr int K     = 16;              // number of reflections
constexpr int RR    = 4;               // rows per wave (amortize LDS v-reads)
constexpr int CH    = D / (64 * 4);    // 8 float4 chunks per lane per row
constexpr int NROWS = 4 * 4096;        // B * S = 16384
constexpr int TPB   = 512;             // 8 waves/block, 1 block/CU (LDS-bound)
constexpr int WPB   = TPB / 64;        // 8 waves
constexpr int NBLK  = 256;             // persistent: one block per CU
constexpr int NBATCH= NROWS / (NBLK * WPB * RR);   // 2 batches
constexpr int SPAD  = 9;               // 8 folded partials + 1 pad

// ---------------------------------------------------------------------------
// Kernel 1: Gram matrix G[i][j] = v_i . v_j  (one wave per (i,j) pair).
// ---------------------------------------------------------------------------
__global__ void __launch_bounds__(64) hh_gram_kernel(const float* __restrict__ vecs,
                                                     float* __restrict__ G) {
    int i = blockIdx.x >> 4, j = blockIdx.x & 15;
    int lane = threadIdx.x;
    const float4* a = (const float4*)(vecs + i * D);
    const float4* b = (const float4*)(vecs + j * D);
    float s = 0.f;
#pragma unroll
    for (int c = 0; c < CH; ++c) {
        float4 x = a[c * 64 + lane], y = b[c * 64 + lane];
        s += x.x * y.x + x.y * y.y + x.z * y.z + x.w * y.w;
    }
#pragma unroll
    for (int off = 32; off >= 1; off >>= 1) s += __shfl_xor(s, off);
    if (lane == 0) G[i * K + j] = s;
}

// ---------------------------------------------------------------------------
// Kernel 2: build T (upper triangular): H0..H15 = I - V T V^T (larft).
//   T[k][k] = beta_k = 2 / max(G[k][k], EPS)
//   T[i][k] = -beta_k * sum_{j=i}^{k-1} T[i][j] * G[j][k]   (i < k)
// Lower triangle stays 0 (apply kernel sums over all k).
// ---------------------------------------------------------------------------
__global__ void __launch_bounds__(256) hh_buildT_kernel(const float* __restrict__ G,
                                                        float* __restrict__ T) {
    __shared__ float sG[K * K], sT[K * K];
    int t = threadIdx.x;
    sG[t] = G[t]; sT[t] = 0.f;
    __syncthreads();
    for (int k = 0; k < K; ++k) {
        float beta = 2.f / fmaxf(sG[k * K + k], HH_EPS);
        if (t == k) sT[k * K + k] = beta;
        else if (t < k) {
            float s = 0.f;
            for (int j = t; j < k; ++j) s += sT[t * K + j] * sG[j * K + k];
            sT[t * K + k] = -beta * s;
        }
        __syncthreads();
    }
    T[t] = sT[t];
}

// ---------------------------------------------------------------------------
// Apply kernel: compact-WY, V LDS-resident, RR=4, persistent over 2 batches.
//
// R10 diagnosis: the LDS pipe (1/CU) was ~62% busy while VALU (4 SIMDs) sat
// at 16% — one ds_read_b128 (12 cyc) fed only 8 VALU-cyc-per-CU at RR=2.
// RR=4 doubles FMAs per v-read (balance point is RR~6). TPB=512 keeps the
// block residable at the ~170-reg demand (launch_bounds(512,2) -> 256-reg
// cap; h[4][8]+runtime loops proven no-spill at this cap in R8). Persistent
// 256-block grid stages V once per CU for both row batches. Per-phase
// partials fold 64->8 lanes into per-wave LDS (the R7 no-spill solution).
// LDS: 128 (V) + 18.4 (sP) + 2 + 2 + 1 = 151.4 KB -> 1 block/CU.
// Tripwire: WRITE_SIZE must stay exactly 131072 KB.
// ---------------------------------------------------------------------------
__global__ void __launch_bounds__(512, 2)
hh_apply_wy(const float* __restrict__ h_in, const float* __restrict__ vecs,
            const float* __restrict__ Tmat, float* __restrict__ h_out) {
    __shared__ float4 sv[K * (D / 4)];          // 128 KB: all 16 vectors
    __shared__ float  sP[WPB * RR * K * SPAD];  // 18.4 KB: per-wave partials
    __shared__ float  sD[WPB * RR * K];         // 2 KB: reduced dots
    __shared__ float  sW[WPB * RR * K];         // 2 KB: w = P.T
    __shared__ float  sT[K * K];                // 1 KB

    const int t    = threadIdx.x;
    const int wv   = t >> 6;
    const int lane = t & 63;

    // Stage all of V: linear LDS dest + contiguous global source (rule #21).
    const float4* v4 = (const float4*)vecs;
#pragma unroll
    for (int i = 0; i < K * (D / 4) / TPB; ++i) {   // 16 rounds of 8 KB
        int idx = t + i * TPB;
        __builtin_amdgcn_global_load_lds(
            (const __attribute__((address_space(1))) unsigned int*)(v4 + idx),
            (__attribute__((address_space(3))) unsigned int*)(sv + idx),
            16, 0, 0);
    }
    if (t < K * K) sT[t] = Tmat[t];
    __syncthreads();   // only barrier in the kernel

    float* myP = sP + wv * (RR * K * SPAD);
    float* myD = sD + wv * (RR * K);
    float* myW = sW + wv * (RR * K);

    const int kk  = lane & 15;
    const int seg = lane >> 4;

#pragma unroll 1
    for (int b = 0; b < NBATCH; ++b) {
        const int gw = b * (NBLK * WPB) + blockIdx.x * WPB + wv;
        const size_t rbase = (size_t)gw * RR;

        // h rows into registers (V already resident; loads overlap compute
        // of other waves).
        float4 h[RR][CH];
        const float4* hin4 = (const float4*)h_in;
#pragma unroll
        for (int r = 0; r < RR; ++r)
#pragma unroll
            for (int j = 0; j < CH; ++j)
                h[r][j] = hin4[(rbase + r) * (D / 4) + j * 64 + lane];

        // ---- dot pass: phase k reads v_k from LDS once, feeds 4 rows ---
#pragma unroll 1
        for (int k = 0; k < K; ++k) {
            float ax[RR], ay[RR], az[RR], aw[RR];
#pragma unroll
            for (int r = 0; r < RR; ++r) { ax[r]=0.f; ay[r]=0.f; az[r]=0.f; aw[r]=0.f; }
#pragma unroll
            for (int j = 0; j < CH; ++j) {
                float4 v = sv[k * (D / 4) + j * 64 + lane];
#pragma unroll
                for (int r = 0; r < RR; ++r) {
                    ax[r] += h[r][j].x * v.x; ay[r] += h[r][j].y * v.y;
                    az[r] += h[r][j].z * v.z; aw[r] += h[r][j].w * v.w;
                }
            }
#pragma unroll
            for (int r = 0; r < RR; ++r) {
                float s = (ax[r] + ay[r]) + (az[r] + aw[r]);
                s += __shfl_xor(s, 32); s += __shfl_xor(s, 16); s += __shfl_xor(s, 8);
                if (lane < 8) myP[(r * K + k) * SPAD + lane] = s;
            }
        }

        // ---- final reduce: lane l -> k=l&15, segment l>>4 reads 2 of 8 -
#pragma unroll
        for (int r = 0; r < RR; ++r) {
            float s = myP[(r * K + kk) * SPAD + seg * 2]
                    + myP[(r * K + kk) * SPAD + seg * 2 + 1];
            s += __shfl_xor(s, 16);
            s += __shfl_xor(s, 32);
            if (lane < 16) myD[r * K + kk] = s;
        }

        // ---- w[j] = sum_k P[k] * T[k][j] (lower triangle of T is 0) ----
#pragma unroll
        for (int r = 0; r < RR; ++r) {
            float wsum = 0.f;
#pragma unroll
            for (int k2 = 0; k2 < K; ++k2)
                wsum += myD[r * K + k2] * sT[k2 * K + kk];   // uniform bcast
            if (lane < 16) myW[r * K + kk] = wsum;
        }

        // ---- update pass: h -= sum_k w_k v_k, v from LDS ---------------
#pragma unroll 1
        for (int k = 0; k < K; ++k) {
            float w[RR];
#pragma unroll
            for (int r = 0; r < RR; ++r) w[r] = myW[r * K + k];   // bcast
#pragma unroll
            for (int j = 0; j < CH; ++j) {
                float4 v = sv[k * (D / 4) + j * 64 + lane];
#pragma unroll
                for (int r = 0; r < RR; ++r) {
                    h[r][j].x -= w[r] * v.x; h[r][j].y -= w[r] * v.y;
                    h[r][j].z -= w[r] * v.z; h[r][j].w -= w[r] * v.w;
                }
            }
        }

        // ---- store ------------------------------------------------------
#pragma unroll
        for (int r = 0; r < RR; ++r) {
            float4* row = (float4*)h_out + (rbase + r) * (D / 4);
#pragma unroll
            for (int j = 0; j < CH; ++j)
                row[j * 64 + lane] = h[r][j];
        }
    }
}

extern "C" void kernel_launch(void* const* d_in, const int* in_sizes, int n_in,
                              void* d_out, int out_size, void* d_ws, size_t ws_size,
                              hipStream_t stream) {
    const float* h    = (const float*)d_in[0];   // [4,4096,2048] fp32
    const float* vecs = (const float*)d_in[1];   // [16,2048] fp32
    float* out        = (float*)d_out;           // [4,4096,2048] fp32

    float* G  = (float*)d_ws;                    // 256 floats
    float* Tm = G + K * K;                       // 256 floats

    hh_gram_kernel<<<K * K, 64, 0, stream>>>(vecs, G);
    hh_buildT_kernel<<<1, 256, 0, stream>>>(G, Tm);

    hh_apply_wy<<<NBLK, TPB, 0, stream>>>(h, vecs, Tm, out);
}